// Round 1
// baseline (1471.655 us; speedup 1.0000x reference)
//
#include <hip/hip_runtime.h>
#include <math.h>

#define BB 2
#define LL 2048
#define DD 1024
#define HH 16
#define DHD 64
#define NT (BB*LL)
#define D3 (3*DD)

__device__ __forceinline__ float wred(float v) {
#pragma unroll
    for (int off = 32; off > 0; off >>= 1) v += __shfl_down(v, off, 64);
    return v;
}

// -------------------- LayerNorm (x -> h) --------------------
__global__ __launch_bounds__(256) void ln_kernel(
        const float* __restrict__ x, const float* __restrict__ w,
        const float* __restrict__ b, float* __restrict__ h) {
    const int t = blockIdx.x;
    const int tid = threadIdx.x;
    const float4 v = ((const float4*)(x + (size_t)t * DD))[tid];
    float s = v.x + v.y + v.z + v.w;
    float ss = v.x*v.x + v.y*v.y + v.z*v.z + v.w*v.w;
    s = wred(s); ss = wred(ss);
    __shared__ float red[8];
    if ((tid & 63) == 0) { red[tid >> 6] = s; red[4 + (tid >> 6)] = ss; }
    __syncthreads();
    s  = red[0] + red[1] + red[2] + red[3];
    ss = red[4] + red[5] + red[6] + red[7];
    const float mu  = s * (1.0f / DD);
    const float inv = rsqrtf(ss * (1.0f / DD) - mu * mu + 1e-5f);
    const float4 wv = ((const float4*)w)[tid];
    const float4 bv = ((const float4*)b)[tid];
    float4 o;
    o.x = (v.x - mu) * inv * wv.x + bv.x;
    o.y = (v.y - mu) * inv * wv.y + bv.y;
    o.z = (v.z - mu) * inv * wv.z + bv.z;
    o.w = (v.w - mu) * inv * wv.w + bv.w;
    ((float4*)(h + (size_t)t * DD))[tid] = o;
}

// -------------------- C[M,N] = A[M,K] * B[N,K]^T (fp32 tiled) --------------------
// 64x64 tile, BK=16, 256 threads, 4x4 microtile per thread.
__global__ __launch_bounds__(256) void gemm_bt(
        const float* __restrict__ A, const float* __restrict__ Bm,
        float* __restrict__ C, int M, int N, int K) {
    __shared__ float As[16][68];   // [k][m], stride 68 keeps float4 alignment, spreads banks
    __shared__ float Bs[16][68];   // [k][n]
    const int tid = threadIdx.x;
    const int tx = tid & 15, ty = tid >> 4;
    const int m0 = blockIdx.y << 6, n0 = blockIdx.x << 6;
    const int lr = tid >> 2;          // 0..63 tile row
    const int lk = (tid & 3) << 2;    // 0,4,8,12
    const float* Ap = A  + (size_t)(m0 + lr) * K + lk;
    const float* Bp = Bm + (size_t)(n0 + lr) * K + lk;
    float acc[4][4] = {};
    for (int k0 = 0; k0 < K; k0 += 16) {
        const float4 a  = *(const float4*)(Ap + k0);
        const float4 bv = *(const float4*)(Bp + k0);
        As[lk + 0][lr] = a.x;  As[lk + 1][lr] = a.y;  As[lk + 2][lr] = a.z;  As[lk + 3][lr] = a.w;
        Bs[lk + 0][lr] = bv.x; Bs[lk + 1][lr] = bv.y; Bs[lk + 2][lr] = bv.z; Bs[lk + 3][lr] = bv.w;
        __syncthreads();
#pragma unroll
        for (int k = 0; k < 16; k++) {
            const float4 av = *(const float4*)&As[k][ty << 2];
            const float4 bw = *(const float4*)&Bs[k][tx << 2];
            const float am[4] = {av.x, av.y, av.z, av.w};
            const float bn[4] = {bw.x, bw.y, bw.z, bw.w};
#pragma unroll
            for (int i = 0; i < 4; i++)
#pragma unroll
                for (int j = 0; j < 4; j++)
                    acc[i][j] += am[i] * bn[j];
        }
        __syncthreads();
    }
#pragma unroll
    for (int i = 0; i < 4; i++)
        *(float4*)(C + (size_t)(m0 + (ty << 2) + i) * N + n0 + (tx << 2)) =
            make_float4(acc[i][0], acc[i][1], acc[i][2], acc[i][3]);
}

// -------------------- per-token Q/K LayerNorm + NeoX RoPE, in place on qkv --------------------
__global__ __launch_bounds__(256) void qk_rope_kernel(
        float* __restrict__ qkv, const float* __restrict__ qw,
        const float* __restrict__ kw) {
    const int t = blockIdx.x;
    const int l = t & (LL - 1);
    const int tid = threadIdx.x;
    float* base = qkv + (size_t)t * D3;
    const float4 qv = ((const float4*)base)[tid];
    const float4 kv = ((const float4*)(base + DD))[tid];
    float sq = qv.x+qv.y+qv.z+qv.w, ssq = qv.x*qv.x+qv.y*qv.y+qv.z*qv.z+qv.w*qv.w;
    float sk = kv.x+kv.y+kv.z+kv.w, ssk = kv.x*kv.x+kv.y*kv.y+kv.z*kv.z+kv.w*kv.w;
    sq = wred(sq); ssq = wred(ssq); sk = wred(sk); ssk = wred(ssk);
    __shared__ float red[16];
    __shared__ float qs[DD], ks[DD];
    const int wid = tid >> 6;
    if ((tid & 63) == 0) { red[wid] = sq; red[4+wid] = ssq; red[8+wid] = sk; red[12+wid] = ssk; }
    __syncthreads();
    sq = red[0]+red[1]+red[2]+red[3];    ssq = red[4]+red[5]+red[6]+red[7];
    sk = red[8]+red[9]+red[10]+red[11];  ssk = red[12]+red[13]+red[14]+red[15];
    const float muq = sq * (1.f/DD), invq = rsqrtf(ssq*(1.f/DD) - muq*muq + 1e-5f);
    const float muk = sk * (1.f/DD), invk = rsqrtf(ssk*(1.f/DD) - muk*muk + 1e-5f);
    const float4 qwv = ((const float4*)qw)[tid];
    const float4 kwv = ((const float4*)kw)[tid];
    float4 qn, kn;
    qn.x = (qv.x-muq)*invq*qwv.x; qn.y = (qv.y-muq)*invq*qwv.y;
    qn.z = (qv.z-muq)*invq*qwv.z; qn.w = (qv.w-muq)*invq*qwv.w;
    kn.x = (kv.x-muk)*invk*kwv.x; kn.y = (kv.y-muk)*invk*kwv.y;
    kn.z = (kv.z-muk)*invk*kwv.z; kn.w = (kv.w-muk)*invk*kwv.w;
    ((float4*)qs)[tid] = qn;
    ((float4*)ks)[tid] = kn;
    __syncthreads();
    const int d  = tid * 4;
    const int j0 = d & 63;                 // position within head
    const bool first = (j0 < 32);
    const int pt = first ? (tid + 8) : (tid - 8);   // partner float4 (d +/- 32)
    const float4 qp = ((const float4*)qs)[pt];
    const float4 kp = ((const float4*)ks)[pt];
    const float qa[4] = {qn.x, qn.y, qn.z, qn.w};
    const float qb[4] = {qp.x, qp.y, qp.z, qp.w};
    const float ka[4] = {kn.x, kn.y, kn.z, kn.w};
    const float kb[4] = {kp.x, kp.y, kp.z, kp.w};
    float oq[4], ok[4];
    const float lf = (float)l;
#pragma unroll
    for (int e = 0; e < 4; e++) {
        const float fi   = (float)((j0 & 31) + e);
        const float freq = expf(fi * (-0.28782313662425576f));   // 10000^(-i/32)
        const float ang  = lf * freq;
        const float c = cosf(ang), sn = sinf(ang);
        if (first) { oq[e] = qa[e]*c - qb[e]*sn; ok[e] = ka[e]*c - kb[e]*sn; }
        else       { oq[e] = qa[e]*c + qb[e]*sn; ok[e] = ka[e]*c + kb[e]*sn; }
    }
    ((float4*)base)[tid]        = make_float4(oq[0], oq[1], oq[2], oq[3]);
    ((float4*)(base + DD))[tid] = make_float4(ok[0], ok[1], ok[2], ok[3]);
}

// -------------------- flash-style fp32 attention --------------------
// grid (L/64, B*H); block 256. Q/K/V read straight out of qkv [B,L,3D].
__global__ __launch_bounds__(256) void attn_kernel(
        const float* __restrict__ qkv, float* __restrict__ ctx) {
    const int bh = blockIdx.y;
    const int b = bh >> 4, hh = bh & 15;
    const int q0 = blockIdx.x * 64;
    const int tid = threadIdx.x;
    const int tx = tid & 15, ty = tid >> 4;    // S-compute mapping (4x4 microtile)
    const int r = tid & 63, seg = tid >> 6;    // softmax/PV mapping: row r, d-segment seg*16
    __shared__ float Qs[64][68];
    __shared__ float KSs[64][68];              // K tile, then reused as S/P (stored [c][r])
    __shared__ float Vs[64][68];
    __shared__ float partA[4][64];
    __shared__ float partB[4][64];
    const float* base = qkv + (size_t)b * LL * D3 + (size_t)hh * DHD;
    // stage Q tile, pre-scaled by 1/sqrt(DH)
#pragma unroll
    for (int i = 0; i < 4; i++) {
        const int f = tid + 256 * i;
        const int row = f >> 4, c4 = (f & 15) << 2;
        float4 q = *(const float4*)(base + (size_t)(q0 + row) * D3 + c4);
        q.x *= 0.125f; q.y *= 0.125f; q.z *= 0.125f; q.w *= 0.125f;
        *(float4*)&Qs[row][c4] = q;
    }
    float m_i = -INFINITY, l_i = 0.0f;
    float o[4][4] = {};
    for (int kt = 0; kt < LL / 64; kt++) {
        __syncthreads();                       // Qs visible (kt=0); KSs/Vs free from prev iter
        const int k0 = kt * 64;
#pragma unroll
        for (int i = 0; i < 4; i++) {
            const int f = tid + 256 * i;
            const int row = f >> 4, c4 = (f & 15) << 2;
            const float* rp = base + (size_t)(k0 + row) * D3 + c4;
            *(float4*)&KSs[row][c4] = *(const float4*)(rp + DD);
            *(float4*)&Vs[row][c4]  = *(const float4*)(rp + 2 * DD);
        }
        __syncthreads();
        // S = Q K^T ; thread covers rows ty*4+i, cols tx+16*j (strided cols: bank-friendly)
        float acc[4][4] = {};
#pragma unroll
        for (int k4 = 0; k4 < 16; k4++) {
            float4 aa[4], bb[4];
#pragma unroll
            for (int i = 0; i < 4; i++) aa[i] = *(const float4*)&Qs[ty*4 + i][k4*4];
#pragma unroll
            for (int j = 0; j < 4; j++) bb[j] = *(const float4*)&KSs[tx + 16*j][k4*4];
#pragma unroll
            for (int i = 0; i < 4; i++)
#pragma unroll
                for (int j = 0; j < 4; j++)
                    acc[i][j] += aa[i].x*bb[j].x + aa[i].y*bb[j].y
                               + aa[i].z*bb[j].z + aa[i].w*bb[j].w;
        }
        __syncthreads();                       // done reading K
        // store S transposed: Ss[c][r]
#pragma unroll
        for (int j = 0; j < 4; j++)
            *(float4*)&KSs[tx + 16*j][ty*4] =
                make_float4(acc[0][j], acc[1][j], acc[2][j], acc[3][j]);
        __syncthreads();
        // online softmax, row r, columns seg*16..+15
        float sv[16];
        float pm = -INFINITY;
#pragma unroll
        for (int cc = 0; cc < 16; cc++) { sv[cc] = KSs[seg*16 + cc][r]; pm = fmaxf(pm, sv[cc]); }
        partA[seg][r] = pm;
        __syncthreads();
        const float tm = fmaxf(fmaxf(partA[0][r], partA[1][r]), fmaxf(partA[2][r], partA[3][r]));
        const float new_m = fmaxf(m_i, tm);
        const float alpha = __expf(m_i - new_m);
        float psum = 0.0f;
#pragma unroll
        for (int cc = 0; cc < 16; cc++) {
            const float p = __expf(sv[cc] - new_m);
            psum += p;
            KSs[seg*16 + cc][r] = p;           // P back to LDS (same [c][r] layout)
        }
        partB[seg][r] = psum;
        __syncthreads();
        l_i = l_i * alpha + (partB[0][r] + partB[1][r] + partB[2][r] + partB[3][r]);
        m_i = new_m;
#pragma unroll
        for (int i = 0; i < 4; i++)
#pragma unroll
            for (int j = 0; j < 4; j++) o[i][j] *= alpha;
        // O[r][seg*16+*] += P[r][:] * V[:][seg*16+*]
#pragma unroll 8
        for (int c = 0; c < 64; c++) {
            const float p = KSs[c][r];
#pragma unroll
            for (int q4 = 0; q4 < 4; q4++) {
                const float4 vv = *(const float4*)&Vs[c][seg*16 + q4*4];
                o[q4][0] += p * vv.x; o[q4][1] += p * vv.y;
                o[q4][2] += p * vv.z; o[q4][3] += p * vv.w;
            }
        }
    }
    const float invl = 1.0f / l_i;
    float* outp = ctx + ((size_t)(b * LL + q0 + r)) * DD + hh * DHD + seg * 16;
#pragma unroll
    for (int q4 = 0; q4 < 4; q4++)
        *(float4*)(outp + q4*4) =
            make_float4(o[q4][0]*invl, o[q4][1]*invl, o[q4][2]*invl, o[q4][3]*invl);
}

extern "C" void kernel_launch(void* const* d_in, const int* in_sizes, int n_in,
                              void* d_out, int out_size, void* d_ws, size_t ws_size,
                              hipStream_t stream) {
    const float* x      = (const float*)d_in[0];
    const float* ln_w   = (const float*)d_in[1];
    const float* ln_b   = (const float*)d_in[2];
    const float* w_qkv  = (const float*)d_in[3];
    const float* q_ln_w = (const float*)d_in[4];
    const float* k_ln_w = (const float*)d_in[5];
    const float* w_out  = (const float*)d_in[6];
    float* out = (float*)d_out;

    // workspace: h (16 MB, reused as ctx) | qkv (48 MB). total 64 MB.
    float* h   = (float*)d_ws;
    float* qkv = (float*)((char*)d_ws + (size_t)NT * DD * sizeof(float));

    ln_kernel<<<NT, 256, 0, stream>>>(x, ln_w, ln_b, h);
    gemm_bt<<<dim3(D3/64, NT/64), 256, 0, stream>>>(h, w_qkv, qkv, NT, D3, DD);
    qk_rope_kernel<<<NT, 256, 0, stream>>>(qkv, q_ln_w, k_ln_w);
    attn_kernel<<<dim3(LL/64, BB*HH), 256, 0, stream>>>(qkv, h /*ctx*/);
    gemm_bt<<<dim3(DD/64, NT/64), 256, 0, stream>>>(h /*ctx*/, w_out, out, NT, DD, DD);
}

// Round 2
// 404.590 us; speedup vs baseline: 3.6374x; 3.6374x over previous
//
#include <hip/hip_runtime.h>
#include <math.h>

#define BB 2
#define LL 2048
#define DD 1024
#define HH 16
#define DHD 64
#define NT (BB*LL)
#define D3 (3*DD)

typedef __bf16 bf16x8 __attribute__((ext_vector_type(8)));
typedef float  f32x4  __attribute__((ext_vector_type(4)));

__device__ __forceinline__ f32x4 mfma16(bf16x8 a, bf16x8 b, f32x4 c) {
    return __builtin_amdgcn_mfma_f32_16x16x32_bf16(a, b, c, 0, 0, 0);
}

__device__ __forceinline__ unsigned short f2bf(float f) {
    unsigned int u = __float_as_uint(f);
    u = (u + 0x7FFFu + ((u >> 16) & 1u)) >> 16;
    return (unsigned short)u;
}
__device__ __forceinline__ float bf2f(unsigned short s) {
    return __uint_as_float(((unsigned int)s) << 16);
}

__device__ __forceinline__ void gload16(const void* g, void* l) {
    __builtin_amdgcn_global_load_lds(
        (const __attribute__((address_space(1))) void*)g,
        (__attribute__((address_space(3))) void*)l, 16, 0, 0);
}

__device__ __forceinline__ float wred(float v) {
#pragma unroll
    for (int off = 32; off > 0; off >>= 1) v += __shfl_down(v, off, 64);
    return v;
}

// -------------------- fp32 -> bf16 convert (weights) --------------------
__global__ __launch_bounds__(256) void cvt_bf16(const float* __restrict__ src,
                                                unsigned short* __restrict__ dst, int n4) {
    const int i = blockIdx.x * 256 + threadIdx.x;
    if (i < n4) {
        const float4 v = ((const float4*)src)[i];
        ((ushort4*)dst)[i] = make_ushort4(f2bf(v.x), f2bf(v.y), f2bf(v.z), f2bf(v.w));
    }
}

// -------------------- LayerNorm (x fp32 -> h bf16) --------------------
__global__ __launch_bounds__(256) void ln_kernel(
        const float* __restrict__ x, const float* __restrict__ w,
        const float* __restrict__ b, unsigned short* __restrict__ h) {
    const int t = blockIdx.x;
    const int tid = threadIdx.x;
    const float4 v = ((const float4*)(x + (size_t)t * DD))[tid];
    float s = v.x + v.y + v.z + v.w;
    float ss = v.x*v.x + v.y*v.y + v.z*v.z + v.w*v.w;
    s = wred(s); ss = wred(ss);
    __shared__ float red[8];
    if ((tid & 63) == 0) { red[tid >> 6] = s; red[4 + (tid >> 6)] = ss; }
    __syncthreads();
    s  = red[0] + red[1] + red[2] + red[3];
    ss = red[4] + red[5] + red[6] + red[7];
    const float mu  = s * (1.0f / DD);
    const float inv = rsqrtf(ss * (1.0f / DD) - mu * mu + 1e-5f);
    const float4 wv = ((const float4*)w)[tid];
    const float4 bv = ((const float4*)b)[tid];
    *(ushort4*)(h + (size_t)t * DD + tid * 4) = make_ushort4(
        f2bf((v.x - mu) * inv * wv.x + bv.x),
        f2bf((v.y - mu) * inv * wv.y + bv.y),
        f2bf((v.z - mu) * inv * wv.z + bv.z),
        f2bf((v.w - mu) * inv * wv.w + bv.w));
}

// -------------------- bf16 MFMA GEMM: C[M,N] = A[M,K] * B[N,K]^T --------------------
// m97 recipe: 128x128 tile, BK=32, 256 thr (4 waves 2x2), global_load_lds(16B) staging.
template<bool BF16OUT>
__global__ __launch_bounds__(256) void gemm_mfma(
        const unsigned short* __restrict__ A, const unsigned short* __restrict__ B,
        void* __restrict__ C, int M, int N, int K) {
    __shared__ unsigned short As[128 * 32];
    __shared__ unsigned short Bs[128 * 32];
    const int tid = threadIdx.x;
    const int w = tid >> 6, lane = tid & 63;
    const int l15 = lane & 15, quad = lane >> 4;
    const int wr = w >> 1, wc = w & 1;
    const int m0 = blockIdx.y << 7, n0 = blockIdx.x << 7;

    // staging: wave w covers tile rows [w*32, w*32+32)
    const int srow = w * 32 + (lane >> 2);
    const int skel = (lane & 3) << 3;
    const unsigned short* gA = A + (size_t)(m0 + srow) * K + skel;
    const unsigned short* gB = B + (size_t)(n0 + srow) * K + skel;
    unsigned short* lA = &As[w * 1024];
    unsigned short* lB = &Bs[w * 1024];

    f32x4 acc[4][4];
#pragma unroll
    for (int i = 0; i < 4; i++)
#pragma unroll
        for (int j = 0; j < 4; j++) acc[i][j] = (f32x4){0.f, 0.f, 0.f, 0.f};

    for (int k0 = 0; k0 < K; k0 += 32) {
        gload16(gA + k0,                 lA);
        gload16(gA + k0 + (size_t)16*K,  lA + 512);
        gload16(gB + k0,                 lB);
        gload16(gB + k0 + (size_t)16*K,  lB + 512);
        __syncthreads();   // drains vmcnt(0): LDS tiles ready
        bf16x8 af[4], bg[4];
#pragma unroll
        for (int i = 0; i < 4; i++) {
            af[i] = *(const bf16x8*)&As[(wr*64 + i*16 + l15) * 32 + quad*8];
            bg[i] = *(const bf16x8*)&Bs[(wc*64 + i*16 + l15) * 32 + quad*8];
        }
#pragma unroll
        for (int i = 0; i < 4; i++)
#pragma unroll
            for (int j = 0; j < 4; j++)
                acc[i][j] = mfma16(af[i], bg[j], acc[i][j]);
        __syncthreads();   // frags consumed before next stage overwrites
    }
#pragma unroll
    for (int i = 0; i < 4; i++) {
        const int mrow = m0 + wr*64 + i*16 + quad*4;
#pragma unroll
        for (int j = 0; j < 4; j++) {
            const int ncol = n0 + wc*64 + j*16 + l15;
#pragma unroll
            for (int r = 0; r < 4; r++) {
                if (BF16OUT)
                    ((unsigned short*)C)[(size_t)(mrow + r) * N + ncol] = f2bf(acc[i][j][r]);
                else
                    ((float*)C)[(size_t)(mrow + r) * N + ncol] = acc[i][j][r];
            }
        }
    }
}

// -------------------- Q/K LayerNorm + NeoX RoPE, in place on qkv bf16 --------------------
// Q additionally pre-scaled by 1/sqrt(DH) = 0.125.
__global__ __launch_bounds__(256) void qk_rope_kernel(
        unsigned short* __restrict__ qkvb,
        const float* __restrict__ qw, const float* __restrict__ kw) {
    const int t = blockIdx.x;
    const int l = t & (LL - 1);
    const int tid = threadIdx.x;
    unsigned short* base = qkvb + (size_t)t * D3;
    const ushort4 qu = *(const ushort4*)(base + tid * 4);
    const ushort4 ku = *(const ushort4*)(base + DD + tid * 4);
    const float q[4] = {bf2f(qu.x), bf2f(qu.y), bf2f(qu.z), bf2f(qu.w)};
    const float k[4] = {bf2f(ku.x), bf2f(ku.y), bf2f(ku.z), bf2f(ku.w)};
    float sq = q[0]+q[1]+q[2]+q[3], ssq = q[0]*q[0]+q[1]*q[1]+q[2]*q[2]+q[3]*q[3];
    float sk = k[0]+k[1]+k[2]+k[3], ssk = k[0]*k[0]+k[1]*k[1]+k[2]*k[2]+k[3]*k[3];
    sq = wred(sq); ssq = wred(ssq); sk = wred(sk); ssk = wred(ssk);
    __shared__ float red[16];
    __shared__ float qs[DD], ks[DD];
    const int wid = tid >> 6;
    if ((tid & 63) == 0) { red[wid] = sq; red[4+wid] = ssq; red[8+wid] = sk; red[12+wid] = ssk; }
    __syncthreads();
    sq = red[0]+red[1]+red[2]+red[3];    ssq = red[4]+red[5]+red[6]+red[7];
    sk = red[8]+red[9]+red[10]+red[11];  ssk = red[12]+red[13]+red[14]+red[15];
    const float muq = sq * (1.f/DD), invq = rsqrtf(ssq*(1.f/DD) - muq*muq + 1e-5f);
    const float muk = sk * (1.f/DD), invk = rsqrtf(ssk*(1.f/DD) - muk*muk + 1e-5f);
    const float4 qwv = ((const float4*)qw)[tid];
    const float4 kwv = ((const float4*)kw)[tid];
    const float qwa[4] = {qwv.x, qwv.y, qwv.z, qwv.w};
    const float kwa[4] = {kwv.x, kwv.y, kwv.z, kwv.w};
    float qn[4], kn[4];
#pragma unroll
    for (int e = 0; e < 4; e++) {
        qn[e] = (q[e] - muq) * invq * qwa[e];
        kn[e] = (k[e] - muk) * invk * kwa[e];
    }
    *(float4*)&qs[tid*4] = make_float4(qn[0], qn[1], qn[2], qn[3]);
    *(float4*)&ks[tid*4] = make_float4(kn[0], kn[1], kn[2], kn[3]);
    __syncthreads();
    const int d = tid * 4, j0 = d & 63;
    const bool first = (j0 < 32);
    const int pt = first ? (tid + 8) : (tid - 8);
    const float4 qp4 = *(const float4*)&qs[pt*4];
    const float4 kp4 = *(const float4*)&ks[pt*4];
    const float qb[4] = {qp4.x, qp4.y, qp4.z, qp4.w};
    const float kb[4] = {kp4.x, kp4.y, kp4.z, kp4.w};
    const float lf = (float)l;
    unsigned short oq[4], ok[4];
#pragma unroll
    for (int e = 0; e < 4; e++) {
        const float fi   = (float)((j0 & 31) + e);
        const float freq = expf(fi * (-0.28782313662425576f));   // 10000^(-i/32)
        const float ang  = lf * freq;
        const float c = cosf(ang), sn = sinf(ang);
        float vq, vk;
        if (first) { vq = qn[e]*c - qb[e]*sn; vk = kn[e]*c - kb[e]*sn; }
        else       { vq = qn[e]*c + qb[e]*sn; vk = kn[e]*c + kb[e]*sn; }
        oq[e] = f2bf(vq * 0.125f);
        ok[e] = f2bf(vk);
    }
    *(ushort4*)(base + tid*4)      = make_ushort4(oq[0], oq[1], oq[2], oq[3]);
    *(ushort4*)(base + DD + tid*4) = make_ushort4(ok[0], ok[1], ok[2], ok[3]);
}

// -------------------- V transpose: qkv v-part [B,L,H,DH] -> vt [B,H,DH,L] --------------------
__global__ __launch_bounds__(256) void vtrans_kernel(
        const unsigned short* __restrict__ qkvb, unsigned short* __restrict__ vt) {
    __shared__ unsigned short T[64][72];
    const int bh = blockIdx.y, b = bh >> 4, h = bh & 15;
    const int l0 = blockIdx.x << 6;
    const int t = threadIdx.x;
    {
        const int r = t >> 2, c16 = (t & 3) << 4;
        const unsigned short* src = qkvb + (size_t)(b*LL + l0 + r) * D3 + 2*DD + h*DHD + c16;
        *(uint4*)&T[r][c16]     = *(const uint4*)src;
        *(uint4*)&T[r][c16 + 8] = *(const uint4*)(src + 8);
    }
    __syncthreads();
    const int dh = t >> 2, l16 = (t & 3) << 4;
    unsigned short tmp[16];
#pragma unroll
    for (int i = 0; i < 16; i++) tmp[i] = T[l16 + i][dh];
    unsigned short* dst = vt + ((size_t)bh * DHD + dh) * LL + l0 + l16;
    *(uint4*)dst       = *(uint4*)&tmp[0];
    *(uint4*)(dst + 8) = *(uint4*)&tmp[8];
}

// -------------------- MFMA flash attention --------------------
// grid (L/64, B*H), 256 thr = 4 waves; wave w owns q rows [q0+w*16, q0+w*16+16).
// S^T = K·Q^T so softmax stats live at col=lane&15 (one q-row per lane).
// Zero __syncthreads in the main loop: P/alpha LDS traffic is wave-private.
__global__ __launch_bounds__(256) void attn_kernel(
        const unsigned short* __restrict__ qkvb,
        const unsigned short* __restrict__ vt,
        unsigned short* __restrict__ ctxb) {
    const int bh = blockIdx.y, b = bh >> 4, h = bh & 15;
    const int q0 = blockIdx.x << 6;
    const int tid = threadIdx.x;
    const int w = tid >> 6, lane = tid & 63;
    const int l15 = lane & 15, quad = lane >> 4;

    __shared__ unsigned short Pw[4][16][72];   // pitch 144 B: 16B-aligned b128 reads, 2-way banks
    __shared__ float Al[4][16];
    __shared__ float Sl[4][16];

    // Q B-frags (kept in regs; Q pre-scaled by 0.125 in rope kernel)
    const unsigned short* qp = qkvb + (size_t)(b*LL + q0 + w*16 + l15) * D3 + h*DHD + quad*8;
    const bf16x8 bq0 = *(const bf16x8*)qp;
    const bf16x8 bq1 = *(const bf16x8*)(qp + 32);

    const unsigned short* kp = qkvb + ((size_t)b*LL + l15) * D3 + DD + h*DHD + quad*8;
    const unsigned short* vp = vt + ((size_t)bh * DHD + l15) * LL + quad*8;

    float m_i = -1e30f, l_i = 0.f;
    f32x4 o[4];
#pragma unroll
    for (int nt = 0; nt < 4; nt++) o[nt] = (f32x4){0.f, 0.f, 0.f, 0.f};

    for (int kt = 0; kt < LL/64; kt++) {
        // ---- S^T tiles: st[t][r] = S[q = w*16+l15][kv = kt*64 + t*16 + quad*4 + r]
        f32x4 st[4];
        const unsigned short* ka = kp;
#pragma unroll
        for (int t = 0; t < 4; t++) {
            const bf16x8 a0 = *(const bf16x8*)ka;
            const bf16x8 a1 = *(const bf16x8*)(ka + 32);
            f32x4 z = (f32x4){0.f, 0.f, 0.f, 0.f};
            z = mfma16(a0, bq0, z);
            z = mfma16(a1, bq1, z);
            st[t] = z;
            ka += (size_t)16 * D3;
        }
        kp += (size_t)64 * D3;

        // ---- online softmax (per-lane row stats + cross-quad shuffle reduce)
        float vmax = st[0][0];
#pragma unroll
        for (int t = 0; t < 4; t++)
#pragma unroll
            for (int r = 0; r < 4; r++) vmax = fmaxf(vmax, st[t][r]);
        vmax = fmaxf(vmax, __shfl_xor(vmax, 16));
        vmax = fmaxf(vmax, __shfl_xor(vmax, 32));
        const float nm = fmaxf(m_i, vmax);
        const float alpha = __expf(m_i - nm);
        m_i = nm;
        float ps = 0.f;
#pragma unroll
        for (int t = 0; t < 4; t++) {
            const float p0 = __expf(st[t][0] - nm);
            const float p1 = __expf(st[t][1] - nm);
            const float p2 = __expf(st[t][2] - nm);
            const float p3 = __expf(st[t][3] - nm);
            ps += (p0 + p1) + (p2 + p3);
            *(ushort4*)&Pw[w][l15][t*16 + quad*4] =
                make_ushort4(f2bf(p0), f2bf(p1), f2bf(p2), f2bf(p3));
        }
        ps += __shfl_xor(ps, 16);
        ps += __shfl_xor(ps, 32);
        l_i = l_i * alpha + ps;
        if (lane < 16) Al[w][lane] = alpha;
        const f32x4 av = *(const f32x4*)&Al[w][quad*4];

        // ---- P·V  (A-frags from wave-private LDS, B-frags direct from vt)
        const bf16x8 ap0 = *(const bf16x8*)&Pw[w][l15][quad*8];
        const bf16x8 ap1 = *(const bf16x8*)&Pw[w][l15][32 + quad*8];
#pragma unroll
        for (int nt = 0; nt < 4; nt++) {
            const unsigned short* vv = vp + (size_t)nt*16*LL;
            f32x4 t0 = o[nt];
            t0[0] *= av[0]; t0[1] *= av[1]; t0[2] *= av[2]; t0[3] *= av[3];
            t0 = mfma16(ap0, *(const bf16x8*)vv, t0);
            t0 = mfma16(ap1, *(const bf16x8*)(vv + 32), t0);
            o[nt] = t0;
        }
        vp += 64;
    }

    if (lane < 16) Sl[w][lane] = l_i;
    const f32x4 lv = *(const f32x4*)&Sl[w][quad*4];
#pragma unroll
    for (int r = 0; r < 4; r++) {
        const float inv = 1.f / lv[r];
        const size_t row = (size_t)(b*LL + q0 + w*16 + quad*4 + r);
#pragma unroll
        for (int nt = 0; nt < 4; nt++)
            ctxb[row * DD + h*DHD + nt*16 + l15] = f2bf(o[nt][r] * inv);
    }
}

extern "C" void kernel_launch(void* const* d_in, const int* in_sizes, int n_in,
                              void* d_out, int out_size, void* d_ws, size_t ws_size,
                              hipStream_t stream) {
    const float* x      = (const float*)d_in[0];
    const float* ln_w   = (const float*)d_in[1];
    const float* ln_b   = (const float*)d_in[2];
    const float* w_qkv  = (const float*)d_in[3];
    const float* q_ln_w = (const float*)d_in[4];
    const float* k_ln_w = (const float*)d_in[5];
    const float* w_out  = (const float*)d_in[6];
    float* out = (float*)d_out;

    // workspace map (48 MB):
    //  [0,8M)   h bf16, later reused as vt [B,H,DH,L] bf16
    //  [8,32M)  qkv bf16 [B,L,3D] (rope in-place)
    //  [32,40M) ctx bf16
    //  [40,46M) w_qkv bf16 ; [46,48M) w_out bf16
    char* ws = (char*)d_ws;
    unsigned short* hb   = (unsigned short*)ws;
    unsigned short* qkvb = (unsigned short*)(ws + ((size_t)8  << 20));
    unsigned short* ctxb = (unsigned short*)(ws + ((size_t)32 << 20));
    unsigned short* wqb  = (unsigned short*)(ws + ((size_t)40 << 20));
    unsigned short* wob  = (unsigned short*)(ws + ((size_t)46 << 20));

    cvt_bf16<<<3072, 256, 0, stream>>>(w_qkv, wqb, 786432);
    cvt_bf16<<<1024, 256, 0, stream>>>(w_out, wob, 262144);
    ln_kernel<<<NT, 256, 0, stream>>>(x, ln_w, ln_b, hb);
    gemm_mfma<true><<<dim3(D3/128, NT/128), 256, 0, stream>>>(hb, wqb, qkvb, NT, D3, DD);
    qk_rope_kernel<<<NT, 256, 0, stream>>>(qkvb, q_ln_w, k_ln_w);
    vtrans_kernel<<<dim3(LL/64, BB*HH), 256, 0, stream>>>(qkvb, hb /*vt*/);
    attn_kernel<<<dim3(LL/64, BB*HH), 256, 0, stream>>>(qkvb, hb /*vt*/, ctxb);
    gemm_mfma<false><<<dim3(DD/128, NT/128), 256, 0, stream>>>(ctxb, wob, out, NT, DD, DD);
}

// Round 3
// 243.734 us; speedup vs baseline: 6.0379x; 1.6600x over previous
//
#include <hip/hip_runtime.h>
#include <math.h>

#define BB 2
#define LL 2048
#define DD 1024
#define HH 16
#define DHD 64
#define NT (BB*LL)
#define D3 (3*DD)
#define D2 (2*DD)

typedef __bf16 bf16x8 __attribute__((ext_vector_type(8)));
typedef float  f32x4  __attribute__((ext_vector_type(4)));

__device__ __forceinline__ f32x4 mfma16(bf16x8 a, bf16x8 b, f32x4 c) {
    return __builtin_amdgcn_mfma_f32_16x16x32_bf16(a, b, c, 0, 0, 0);
}

__device__ __forceinline__ unsigned short f2bf(float f) {
    unsigned int u = __float_as_uint(f);
    u = (u + 0x7FFFu + ((u >> 16) & 1u)) >> 16;
    return (unsigned short)u;
}
__device__ __forceinline__ float bf2f(unsigned short s) {
    return __uint_as_float(((unsigned int)s) << 16);
}

__device__ __forceinline__ void gload16(const void* g, void* l) {
    __builtin_amdgcn_global_load_lds(
        (const __attribute__((address_space(1))) void*)g,
        (__attribute__((address_space(3))) void*)l, 16, 0, 0);
}

__device__ __forceinline__ float wred(float v) {
#pragma unroll
    for (int off = 32; off > 0; off >>= 1) v += __shfl_down(v, off, 64);
    return v;
}

// -------------------- fp32 -> bf16 convert (both weight arrays, one launch) ----
__global__ __launch_bounds__(256) void cvt2_bf16(
        const float* __restrict__ s1, unsigned short* __restrict__ d1, int n1,
        const float* __restrict__ s2, unsigned short* __restrict__ d2, int n2) {
    int i = blockIdx.x * 256 + threadIdx.x;
    const float* s; unsigned short* d;
    if (i < n1) { s = s1; d = d1; }
    else { i -= n1; if (i >= n2) return; s = s2; d = d2; }
    const float4 v = ((const float4*)s)[i];
    ((ushort4*)d)[i] = make_ushort4(f2bf(v.x), f2bf(v.y), f2bf(v.z), f2bf(v.w));
}

// -------------------- LayerNorm (x fp32 -> h bf16) --------------------
__global__ __launch_bounds__(256) void ln_kernel(
        const float* __restrict__ x, const float* __restrict__ w,
        const float* __restrict__ b, unsigned short* __restrict__ h) {
    const int t = blockIdx.x;
    const int tid = threadIdx.x;
    const float4 v = ((const float4*)(x + (size_t)t * DD))[tid];
    float s = v.x + v.y + v.z + v.w;
    float ss = v.x*v.x + v.y*v.y + v.z*v.z + v.w*v.w;
    s = wred(s); ss = wred(ss);
    __shared__ float red[8];
    if ((tid & 63) == 0) { red[tid >> 6] = s; red[4 + (tid >> 6)] = ss; }
    __syncthreads();
    s  = red[0] + red[1] + red[2] + red[3];
    ss = red[4] + red[5] + red[6] + red[7];
    const float mu  = s * (1.0f / DD);
    const float inv = rsqrtf(ss * (1.0f / DD) - mu * mu + 1e-5f);
    const float4 wv = ((const float4*)w)[tid];
    const float4 bv = ((const float4*)b)[tid];
    *(ushort4*)(h + (size_t)t * DD + tid * 4) = make_ushort4(
        f2bf((v.x - mu) * inv * wv.x + bv.x),
        f2bf((v.y - mu) * inv * wv.y + bv.y),
        f2bf((v.z - mu) * inv * wv.z + bv.z),
        f2bf((v.w - mu) * inv * wv.w + bv.w));
}

// -------------------- QKV GEMM: qk[t][2048] + V transposed to vt[B,H,DH,L] ----
__global__ __launch_bounds__(256) void gemm_qkv(
        const unsigned short* __restrict__ A, const unsigned short* __restrict__ B,
        unsigned short* __restrict__ qk, unsigned short* __restrict__ vt) {
    const int K = DD, N = D3;
    __shared__ unsigned short As[128 * 32];
    __shared__ unsigned short Bs[128 * 32];
    const int tid = threadIdx.x;
    const int w = tid >> 6, lane = tid & 63;
    const int l15 = lane & 15, quad = lane >> 4;
    const int wr = w >> 1, wc = w & 1;
    const int m0 = blockIdx.y << 7, n0 = blockIdx.x << 7;

    const int srow = w * 32 + (lane >> 2);
    const int skel = (lane & 3) << 3;
    const unsigned short* gA = A + (size_t)(m0 + srow) * K + skel;
    const unsigned short* gB = B + (size_t)(n0 + srow) * K + skel;
    unsigned short* lA = &As[w * 1024];
    unsigned short* lB = &Bs[w * 1024];

    f32x4 acc[4][4];
#pragma unroll
    for (int i = 0; i < 4; i++)
#pragma unroll
        for (int j = 0; j < 4; j++) acc[i][j] = (f32x4){0.f, 0.f, 0.f, 0.f};

    for (int k0 = 0; k0 < K; k0 += 32) {
        gload16(gA + k0,                 lA);
        gload16(gA + k0 + (size_t)16*K,  lA + 512);
        gload16(gB + k0,                 lB);
        gload16(gB + k0 + (size_t)16*K,  lB + 512);
        __syncthreads();
        bf16x8 af[4], bg[4];
#pragma unroll
        for (int i = 0; i < 4; i++) {
            af[i] = *(const bf16x8*)&As[(wr*64 + i*16 + l15) * 32 + quad*8];
            bg[i] = *(const bf16x8*)&Bs[(wc*64 + i*16 + l15) * 32 + quad*8];
        }
#pragma unroll
        for (int i = 0; i < 4; i++)
#pragma unroll
            for (int j = 0; j < 4; j++)
                acc[i][j] = mfma16(af[i], bg[j], acc[i][j]);
        __syncthreads();
    }
    if (n0 < D2) {
        // q/k part -> qk [token][2048]
#pragma unroll
        for (int i = 0; i < 4; i++) {
            const int mrow = m0 + wr*64 + i*16 + quad*4;
#pragma unroll
            for (int j = 0; j < 4; j++) {
                const int ncol = n0 + wc*64 + j*16 + l15;
#pragma unroll
                for (int r = 0; r < 4; r++)
                    qk[(size_t)(mrow + r) * D2 + ncol] = f2bf(acc[i][j][r]);
            }
        }
    } else {
        // v part -> vt [B,H,DH,L] (transposed store; r is contiguous in L)
#pragma unroll
        for (int i = 0; i < 4; i++) {
            const int mrow = m0 + wr*64 + i*16 + quad*4;
            const int bb = mrow >> 11, l = mrow & (LL - 1);
#pragma unroll
            for (int j = 0; j < 4; j++) {
                const int nv = n0 + wc*64 + j*16 + l15 - D2;
                const int hh = nv >> 6, dh = nv & 63;
                *(ushort4*)&vt[((size_t)(bb*HH + hh) * DHD + dh) * LL + l] =
                    make_ushort4(f2bf(acc[i][j][0]), f2bf(acc[i][j][1]),
                                 f2bf(acc[i][j][2]), f2bf(acc[i][j][3]));
            }
        }
    }
}

// -------------------- out-proj GEMM: C fp32 = A[M,K] * B[N,K]^T ----------------
__global__ __launch_bounds__(256) void gemm_out(
        const unsigned short* __restrict__ A, const unsigned short* __restrict__ B,
        float* __restrict__ C, int M, int N, int K) {
    __shared__ unsigned short As[128 * 32];
    __shared__ unsigned short Bs[128 * 32];
    const int tid = threadIdx.x;
    const int w = tid >> 6, lane = tid & 63;
    const int l15 = lane & 15, quad = lane >> 4;
    const int wr = w >> 1, wc = w & 1;
    const int m0 = blockIdx.y << 7, n0 = blockIdx.x << 7;
    const int srow = w * 32 + (lane >> 2);
    const int skel = (lane & 3) << 3;
    const unsigned short* gA = A + (size_t)(m0 + srow) * K + skel;
    const unsigned short* gB = B + (size_t)(n0 + srow) * K + skel;
    unsigned short* lA = &As[w * 1024];
    unsigned short* lB = &Bs[w * 1024];
    f32x4 acc[4][4];
#pragma unroll
    for (int i = 0; i < 4; i++)
#pragma unroll
        for (int j = 0; j < 4; j++) acc[i][j] = (f32x4){0.f, 0.f, 0.f, 0.f};
    for (int k0 = 0; k0 < K; k0 += 32) {
        gload16(gA + k0,                 lA);
        gload16(gA + k0 + (size_t)16*K,  lA + 512);
        gload16(gB + k0,                 lB);
        gload16(gB + k0 + (size_t)16*K,  lB + 512);
        __syncthreads();
        bf16x8 af[4], bg[4];
#pragma unroll
        for (int i = 0; i < 4; i++) {
            af[i] = *(const bf16x8*)&As[(wr*64 + i*16 + l15) * 32 + quad*8];
            bg[i] = *(const bf16x8*)&Bs[(wc*64 + i*16 + l15) * 32 + quad*8];
        }
#pragma unroll
        for (int i = 0; i < 4; i++)
#pragma unroll
            for (int j = 0; j < 4; j++)
                acc[i][j] = mfma16(af[i], bg[j], acc[i][j]);
        __syncthreads();
    }
#pragma unroll
    for (int i = 0; i < 4; i++) {
        const int mrow = m0 + wr*64 + i*16 + quad*4;
#pragma unroll
        for (int j = 0; j < 4; j++) {
            const int ncol = n0 + wc*64 + j*16 + l15;
#pragma unroll
            for (int r = 0; r < 4; r++)
                C[(size_t)(mrow + r) * N + ncol] = acc[i][j][r];
        }
    }
}

// -------------------- Q/K LayerNorm + NeoX RoPE: qk -> qarr/karr [B,H,L,DH] ----
// Q pre-scaled by 0.125*log2(e) so attention softmax runs in exp2 domain.
__global__ __launch_bounds__(256) void qk_rope_kernel(
        const unsigned short* __restrict__ qk,
        const float* __restrict__ qw, const float* __restrict__ kw,
        unsigned short* __restrict__ qarr, unsigned short* __restrict__ karr) {
    const int t = blockIdx.x;
    const int l = t & (LL - 1), b = t >> 11;
    const int tid = threadIdx.x;
    const unsigned short* base = qk + (size_t)t * D2;
    const ushort4 qu = *(const ushort4*)(base + tid * 4);
    const ushort4 ku = *(const ushort4*)(base + DD + tid * 4);
    const float q[4] = {bf2f(qu.x), bf2f(qu.y), bf2f(qu.z), bf2f(qu.w)};
    const float k[4] = {bf2f(ku.x), bf2f(ku.y), bf2f(ku.z), bf2f(ku.w)};
    float sq = q[0]+q[1]+q[2]+q[3], ssq = q[0]*q[0]+q[1]*q[1]+q[2]*q[2]+q[3]*q[3];
    float sk = k[0]+k[1]+k[2]+k[3], ssk = k[0]*k[0]+k[1]*k[1]+k[2]*k[2]+k[3]*k[3];
    sq = wred(sq); ssq = wred(ssq); sk = wred(sk); ssk = wred(ssk);
    __shared__ float red[16];
    __shared__ float qs[DD], ks[DD];
    const int wid = tid >> 6;
    if ((tid & 63) == 0) { red[wid] = sq; red[4+wid] = ssq; red[8+wid] = sk; red[12+wid] = ssk; }
    __syncthreads();
    sq = red[0]+red[1]+red[2]+red[3];    ssq = red[4]+red[5]+red[6]+red[7];
    sk = red[8]+red[9]+red[10]+red[11];  ssk = red[12]+red[13]+red[14]+red[15];
    const float muq = sq * (1.f/DD), invq = rsqrtf(ssq*(1.f/DD) - muq*muq + 1e-5f);
    const float muk = sk * (1.f/DD), invk = rsqrtf(ssk*(1.f/DD) - muk*muk + 1e-5f);
    const float4 qwv = ((const float4*)qw)[tid];
    const float4 kwv = ((const float4*)kw)[tid];
    const float qwa[4] = {qwv.x, qwv.y, qwv.z, qwv.w};
    const float kwa[4] = {kwv.x, kwv.y, kwv.z, kwv.w};
    float qn[4], kn[4];
#pragma unroll
    for (int e = 0; e < 4; e++) {
        qn[e] = (q[e] - muq) * invq * qwa[e];
        kn[e] = (k[e] - muk) * invk * kwa[e];
    }
    *(float4*)&qs[tid*4] = make_float4(qn[0], qn[1], qn[2], qn[3]);
    *(float4*)&ks[tid*4] = make_float4(kn[0], kn[1], kn[2], kn[3]);
    __syncthreads();
    const int d = tid * 4, j0 = d & 63;
    const bool first = (j0 < 32);
    const int pt = first ? (tid + 8) : (tid - 8);
    const float4 qp4 = *(const float4*)&qs[pt*4];
    const float4 kp4 = *(const float4*)&ks[pt*4];
    const float qb[4] = {qp4.x, qp4.y, qp4.z, qp4.w};
    const float kb[4] = {kp4.x, kp4.y, kp4.z, kp4.w};
    const float lf = (float)l;
    const float QS = 0.125f * 1.44269504088896340736f;   // 1/sqrt(DH) * log2(e)
    unsigned short oq[4], ok[4];
#pragma unroll
    for (int e = 0; e < 4; e++) {
        const float fi   = (float)((j0 & 31) + e);
        const float freq = expf(fi * (-0.28782313662425576f));   // 10000^(-i/32)
        const float ang  = lf * freq;
        const float c = cosf(ang), sn = sinf(ang);
        float vq, vk;
        if (first) { vq = qn[e]*c - qb[e]*sn; vk = kn[e]*c - kb[e]*sn; }
        else       { vq = qn[e]*c + qb[e]*sn; vk = kn[e]*c + kb[e]*sn; }
        oq[e] = f2bf(vq * QS);
        ok[e] = f2bf(vk);
    }
    const int hh = tid >> 4;          // (tid*4)>>6
    const int dh = (tid * 4) & 63;
    const size_t ro = ((size_t)(b*HH + hh) * LL + l) * DHD + dh;
    *(ushort4*)(qarr + ro) = make_ushort4(oq[0], oq[1], oq[2], oq[3]);
    *(ushort4*)(karr + ro) = make_ushort4(ok[0], ok[1], ok[2], ok[3]);
}

// -------------------- MFMA flash attention, staged K/V + reg-prefetch pipeline --
// grid 512 (xcd-swizzled (qblk,bh)); 256 thr = 4 waves; wave owns 32 q-rows.
// K/V tiles (64x64) staged to LDS via global_load_lds with XOR-swizzled 16B
// chunks (conflict-free b128 frag reads). Frags pulled to regs BEFORE the
// overwrite barrier so stage(kt+1) overlaps all of tile kt's compute.
__global__ __launch_bounds__(256) void attn_kernel(
        const unsigned short* __restrict__ qarr,
        const unsigned short* __restrict__ karr,
        const unsigned short* __restrict__ vt,
        unsigned short* __restrict__ ctxb) {
    const int x = blockIdx.x;
    const int bh = (x & 7) + ((x >> 7) << 3);      // 16 q-blocks of one head -> one XCD
    const int q0 = ((x >> 3) & 15) << 7;
    const int b = bh >> 4, h = bh & 15;
    const int tid = threadIdx.x, w = tid >> 6, lane = tid & 63;
    const int l15 = lane & 15, quad = lane >> 4;

    __shared__ unsigned short Ks[64 * 64];
    __shared__ unsigned short Vs[64 * 64];
    __shared__ unsigned short Pw[4][2][16][72];

    const unsigned short* kbase = karr + (size_t)bh * LL * DHD;
    const unsigned short* vbase = vt   + (size_t)bh * DHD * LL;

    // Q frags (B-operand), persistent in regs
    bf16x8 qf[2][2];
    {
        const unsigned short* qp = qarr + ((size_t)bh*LL + q0 + w*32 + l15) * DHD + quad*8;
#pragma unroll
        for (int qt = 0; qt < 2; qt++)
#pragma unroll
            for (int c = 0; c < 2; c++)
                qf[qt][c] = *(const bf16x8*)(qp + qt*16*DHD + c*32);
    }

    const int r8 = lane >> 3, sc = lane & 7;
    float m_i[2] = {-1e30f, -1e30f};
    float l_i[2] = {0.f, 0.f};
    f32x4 o[2][4];
#pragma unroll
    for (int qt = 0; qt < 2; qt++)
#pragma unroll
        for (int nt = 0; nt < 4; nt++) o[qt][nt] = (f32x4){0.f, 0.f, 0.f, 0.f};

    // stage tile 0
#pragma unroll
    for (int rd = 0; rd < 2; rd++) {
        const int row = w*8 + rd*32 + r8;
        const int chunk = sc ^ (row & 7);
        gload16(kbase + (size_t)row * DHD + chunk*8, (char*)Ks + w*1024 + rd*4096);
        gload16(vbase + (size_t)row * LL + chunk*8,  (char*)Vs + w*1024 + rd*4096);
    }

    for (int kt = 0; kt < LL/64; kt++) {
        __syncthreads();                    // staging for tile kt complete
        bf16x8 kf[4][2], vf[4][2];
#pragma unroll
        for (int t = 0; t < 4; t++)
#pragma unroll
            for (int c = 0; c < 2; c++) {
                const int slot = (quad + c*4) ^ (l15 & 7);
                kf[t][c] = *(const bf16x8*)&Ks[(t*16 + l15) * DHD + slot*8];
                vf[t][c] = *(const bf16x8*)&Vs[(t*16 + l15) * DHD + slot*8];
            }
        __syncthreads();                    // all waves done reading LDS
        if (kt + 1 < LL/64) {               // stage kt+1 under this tile's compute
#pragma unroll
            for (int rd = 0; rd < 2; rd++) {
                const int row = w*8 + rd*32 + r8;
                const int chunk = sc ^ (row & 7);
                gload16(kbase + ((size_t)((kt+1)*64 + row)) * DHD + chunk*8,
                        (char*)Ks + w*1024 + rd*4096);
                gload16(vbase + (size_t)row * LL + (kt+1)*64 + chunk*8,
                        (char*)Vs + w*1024 + rd*4096);
            }
        }

        // S^T = K . Q^T  (col = q-row = l15)
        f32x4 st[2][4];
#pragma unroll
        for (int qt = 0; qt < 2; qt++)
#pragma unroll
            for (int t = 0; t < 4; t++) {
                f32x4 z = (f32x4){0.f, 0.f, 0.f, 0.f};
                z = mfma16(kf[t][0], qf[qt][0], z);
                z = mfma16(kf[t][1], qf[qt][1], z);
                st[qt][t] = z;
            }

#pragma unroll
        for (int qt = 0; qt < 2; qt++) {
            float vmax = st[qt][0][0];
#pragma unroll
            for (int t = 0; t < 4; t++)
#pragma unroll
                for (int r = 0; r < 4; r++) vmax = fmaxf(vmax, st[qt][t][r]);
            vmax = fmaxf(vmax, __shfl_xor(vmax, 16));
            vmax = fmaxf(vmax, __shfl_xor(vmax, 32));
            const float nm = fmaxf(m_i[qt], vmax);
            const float alpha = __builtin_amdgcn_exp2f(m_i[qt] - nm);
            m_i[qt] = nm;
            float ps = 0.f;
#pragma unroll
            for (int t = 0; t < 4; t++) {
                const float p0 = __builtin_amdgcn_exp2f(st[qt][t][0] - nm);
                const float p1 = __builtin_amdgcn_exp2f(st[qt][t][1] - nm);
                const float p2 = __builtin_amdgcn_exp2f(st[qt][t][2] - nm);
                const float p3 = __builtin_amdgcn_exp2f(st[qt][t][3] - nm);
                ps += (p0 + p1) + (p2 + p3);
                *(ushort4*)&Pw[w][qt][l15][t*16 + quad*4] =
                    make_ushort4(f2bf(p0), f2bf(p1), f2bf(p2), f2bf(p3));
            }
            ps += __shfl_xor(ps, 16);
            ps += __shfl_xor(ps, 32);
            l_i[qt] = l_i[qt] * alpha + ps;
            float av[4];
#pragma unroll
            for (int r = 0; r < 4; r++) av[r] = __shfl(alpha, quad*4 + r);
            const bf16x8 ap0 = *(const bf16x8*)&Pw[w][qt][l15][quad*8];
            const bf16x8 ap1 = *(const bf16x8*)&Pw[w][qt][l15][32 + quad*8];
#pragma unroll
            for (int nt = 0; nt < 4; nt++) {
                f32x4 t0 = o[qt][nt];
                t0[0] *= av[0]; t0[1] *= av[1]; t0[2] *= av[2]; t0[3] *= av[3];
                t0 = mfma16(ap0, vf[nt][0], t0);
                t0 = mfma16(ap1, vf[nt][1], t0);
                o[qt][nt] = t0;
            }
        }
    }

#pragma unroll
    for (int qt = 0; qt < 2; qt++) {
        float lv[4];
#pragma unroll
        for (int r = 0; r < 4; r++) lv[r] = __shfl(l_i[qt], quad*4 + r);
#pragma unroll
        for (int r = 0; r < 4; r++) {
            const float inv = 1.f / lv[r];
            const size_t row = (size_t)(b*LL + q0 + w*32 + qt*16 + quad*4 + r);
#pragma unroll
            for (int nt = 0; nt < 4; nt++)
                ctxb[row * DD + h*DHD + nt*16 + l15] = f2bf(o[qt][nt][r] * inv);
        }
    }
}

extern "C" void kernel_launch(void* const* d_in, const int* in_sizes, int n_in,
                              void* d_out, int out_size, void* d_ws, size_t ws_size,
                              hipStream_t stream) {
    const float* x      = (const float*)d_in[0];
    const float* ln_w   = (const float*)d_in[1];
    const float* ln_b   = (const float*)d_in[2];
    const float* w_qkv  = (const float*)d_in[3];
    const float* q_ln_w = (const float*)d_in[4];
    const float* k_ln_w = (const float*)d_in[5];
    const float* w_out  = (const float*)d_in[6];
    float* out = (float*)d_out;

    // workspace map (48 MB), with aliased reuse:
    //  [0,8M)   h bf16            -> karr [B,H,L,DH] after gemm_qkv consumed h
    //  [8,24M)  qk bf16 [t][2048] -> first 8M reused as ctx after rope consumed qk
    //  [24,32M) vt bf16 [B,H,DH,L]
    //  [32,40M) qarr bf16 [B,H,L,DH]
    //  [40,46M) w_qkv bf16 ; [46,48M) w_out bf16
    char* ws = (char*)d_ws;
    unsigned short* hb   = (unsigned short*)ws;
    unsigned short* karr = (unsigned short*)ws;                      // aliases hb
    unsigned short* qk   = (unsigned short*)(ws + ((size_t)8  << 20));
    unsigned short* ctxb = (unsigned short*)(ws + ((size_t)8  << 20)); // aliases qk
    unsigned short* vtp  = (unsigned short*)(ws + ((size_t)24 << 20));
    unsigned short* qarr = (unsigned short*)(ws + ((size_t)32 << 20));
    unsigned short* wqb  = (unsigned short*)(ws + ((size_t)40 << 20));
    unsigned short* wob  = (unsigned short*)(ws + ((size_t)46 << 20));

    cvt2_bf16<<<4096, 256, 0, stream>>>(w_qkv, wqb, 786432, w_out, wob, 262144);
    ln_kernel<<<NT, 256, 0, stream>>>(x, ln_w, ln_b, hb);
    gemm_qkv<<<dim3(D3/128, NT/128), 256, 0, stream>>>(hb, wqb, qk, vtp);
    qk_rope_kernel<<<NT, 256, 0, stream>>>(qk, q_ln_w, k_ln_w, qarr, karr);
    attn_kernel<<<512, 256, 0, stream>>>(qarr, karr, vtp, ctxb);
    gemm_out<<<dim3(DD/128, NT/128), 256, 0, stream>>>(ctxb, wob, out, NT, DD, DD);
}